// Round 3
// baseline (544.608 us; speedup 1.0000x reference)
//
#include <hip/hip_runtime.h>

#define NETS 32
#define BATCH 4096
#define D0 256
#define D1 512
#define D2 512
#define D3 128
#define MT 32            // batch rows per block
#define LDA (D0 + 8)     // 264 halves -> 528 B row stride (4-bank rotation per row)
#define LDH (D1 + 8)     // 520 halves -> 1040 B row stride

using half8 = __attribute__((ext_vector_type(8))) _Float16;
using half4 = __attribute__((ext_vector_type(4))) _Float16;
using f32x4 = __attribute__((ext_vector_type(4))) float;

#define W1_N (NETS * D1 * D0)   // 4,194,304
#define W2_N (NETS * D2 * D1)   // 8,388,608
#define W3_N (NETS * D3 * D2)   // 2,097,152
#define W1_4 (W1_N / 4)
#define W2_4 (W2_N / 4)
#define W3_4 (W3_N / 4)

// ---------------- single fused fp32 -> fp16 weight-cast kernel ----------------
__global__ void cvt_weights(const float* __restrict__ W1, const float* __restrict__ W2,
                            const float* __restrict__ W3,
                            _Float16* __restrict__ W1h, _Float16* __restrict__ W2h,
                            _Float16* __restrict__ W3h) {
    int i = blockIdx.x * blockDim.x + threadIdx.x;
    const float* src;
    _Float16* dst;
    int off;
    if (i < W1_4)              { src = W1; dst = W1h; off = i; }
    else if (i < W1_4 + W2_4)  { src = W2; dst = W2h; off = i - W1_4; }
    else                       { src = W3; dst = W3h; off = i - W1_4 - W2_4; }
    float4 v = reinterpret_cast<const float4*>(src)[off];
    half4 o;
    o[0] = (_Float16)v.x; o[1] = (_Float16)v.y;
    o[2] = (_Float16)v.z; o[3] = (_Float16)v.w;
    reinterpret_cast<half4*>(dst)[off] = o;
}

// ---------------- software-pipelined layer ----------------
// B-fragments stream from global (L2) in register groups of G, prefetched one
// step ahead. A-fragments from LDS. Fully unrolled so all offsets const-fold.
template<int K, int NFRAG, int G>
__device__ __forceinline__ void layer_mfma(const _Float16* As, int lda,
                                           const _Float16* __restrict__ wp,  // + n_base*K + lane16*K + quad*8
                                           int lane16, int quad,
                                           f32x4 (&acc)[2][NFRAG]) {
    constexpr int NG = NFRAG / G;          // B groups per kk step
    constexpr int STEPS = (K / 32) * NG;
    half8 bcur[G], bnxt[G];
    half8 a[2];
#pragma unroll
    for (int g = 0; g < G; ++g)
        bcur[g] = *reinterpret_cast<const half8*>(wp + (size_t)g * 16 * K);
#pragma unroll
    for (int s = 0; s < STEPS; ++s) {
        const int kk = s / NG, grp = s % NG;
        if (s + 1 < STEPS) {
            const int nkk = (s + 1) / NG, ngrp = (s + 1) % NG;
#pragma unroll
            for (int g = 0; g < G; ++g)
                bnxt[g] = *reinterpret_cast<const half8*>(
                    wp + (size_t)(ngrp * G + g) * 16 * K + nkk * 32);
        }
        if (grp == 0) {
#pragma unroll
            for (int mi = 0; mi < 2; ++mi)
                a[mi] = *reinterpret_cast<const half8*>(
                    As + (mi * 16 + lane16) * lda + kk * 32 + quad * 8);
        }
#pragma unroll
        for (int g = 0; g < G; ++g) {
            const int ni = grp * G + g;
#pragma unroll
            for (int mi = 0; mi < 2; ++mi)
                acc[mi][ni] = __builtin_amdgcn_mfma_f32_16x16x32_f16(a[mi], bcur[g], acc[mi][ni], 0, 0, 0);
        }
        if (s + 1 < STEPS) {
#pragma unroll
            for (int g = 0; g < G; ++g) bcur[g] = bnxt[g];
        }
    }
}

template<int NFRAG>
__device__ __forceinline__ void store_act(f32x4 (&acc)[2][NFRAG], const float* __restrict__ bias,
                                          _Float16* dst, int ldd, int n_base,
                                          int lane16, int quad) {
#pragma unroll
    for (int ni = 0; ni < NFRAG; ++ni) {
        float bv = bias[n_base + ni * 16 + lane16];
        int col = n_base + ni * 16 + lane16;
#pragma unroll
        for (int mi = 0; mi < 2; ++mi) {
#pragma unroll
            for (int r = 0; r < 4; ++r) {
                float v = acc[mi][ni][r] + bv;
                v = fmaxf(v, 0.0f);                        // relu
                int row = mi * 16 + quad * 4 + r;
                dst[row * ldd + col] = (_Float16)v;
            }
        }
    }
}

// ---------------- fused 3-layer MLP, single in-place LDS buffer ----------------
__global__ __launch_bounds__(256, 3) void mlp_fused(
    const float* __restrict__ X,
    const _Float16* __restrict__ W1h, const float* __restrict__ b1,
    const _Float16* __restrict__ W2h, const float* __restrict__ b2,
    const _Float16* __restrict__ W3h, const float* __restrict__ b3,
    float* __restrict__ out) {
    __shared__ __align__(16) _Float16 buf[MT * LDH];   // X tile (LDA layout) -> H1 -> H2 (LDH)

    const int tid = threadIdx.x;
    const int w = tid >> 6;
    const int l = tid & 63;
    const int lane16 = l & 15;
    const int quad = l >> 4;

    // XCD-locality swizzle: dispatch round-robins blockIdx over 8 XCDs ->
    // pin 4 nets per XCD so each XCD-L2 holds ~3.7 MB of fp16 weights.
    const int bb = blockIdx.x;
    const int xcd = bb & 7;
    const int s = bb >> 3;                // 0..511
    const int net = xcd * 4 + (s >> 7);   // 0..31
    const int mt = s & 127;               // 0..127
    const int m0 = mt * MT;

    // ---- stage X tile [MT][D0] fp32 -> fp16 into buf (LDA layout) ----
    // MT*D0/4 = 2048 float4 chunks; 256 threads x 8 iters.
    {
        const float* xsrc = X + (size_t)m0 * D0;
#pragma unroll
        for (int it = 0; it < 8; ++it) {
            int chunk = it * 256 + tid;   // 0..2047; 64 float4 per row
            int row = chunk >> 6;
            int c4 = chunk & 63;
            float4 v = *reinterpret_cast<const float4*>(xsrc + row * D0 + c4 * 4);
            half4 o;
            o[0] = (_Float16)v.x; o[1] = (_Float16)v.y;
            o[2] = (_Float16)v.z; o[3] = (_Float16)v.w;
            *reinterpret_cast<half4*>(&buf[row * LDA + c4 * 4]) = o;
        }
    }
    __syncthreads();

    // ---- layer 1: H1 = relu(X @ W1^T + b1), K=256, N=512 ----
    {
        f32x4 acc[2][8] = {};
        const _Float16* wp = W1h + (size_t)net * D1 * D0 + (size_t)(w * 128 + lane16) * D0 + quad * 8;
        layer_mfma<D0, 8, 4>(buf, LDA, wp, lane16, quad, acc);
        __syncthreads();                               // all X reads done
        store_act<8>(acc, b1 + net * D1, buf, LDH, w * 128, lane16, quad);
    }
    __syncthreads();

    // ---- layer 2: H2 = relu(H1 @ W2^T + b2), K=512, N=512 ----
    {
        f32x4 acc[2][8] = {};
        const _Float16* wp = W2h + (size_t)net * D2 * D1 + (size_t)(w * 128 + lane16) * D1 + quad * 8;
        layer_mfma<D1, 8, 4>(buf, LDH, wp, lane16, quad, acc);
        __syncthreads();                               // all H1 reads done
        store_act<8>(acc, b2 + net * D2, buf, LDH, w * 128, lane16, quad);
    }
    __syncthreads();

    // ---- layer 3: out = H2 @ W3^T + b3, K=512, N=128, fp32 direct to global ----
    {
        f32x4 acc[2][2] = {};
        const _Float16* wp = W3h + (size_t)net * D3 * D2 + (size_t)(w * 32 + lane16) * D2 + quad * 8;
        layer_mfma<D2, 2, 2>(buf, LDH, wp, lane16, quad, acc);
        const int n_base = w * 32;
#pragma unroll
        for (int ni = 0; ni < 2; ++ni) {
            float bv = b3[net * D3 + n_base + ni * 16 + lane16];
            int col = net * D3 + n_base + ni * 16 + lane16;
#pragma unroll
            for (int mi = 0; mi < 2; ++mi) {
#pragma unroll
                for (int r = 0; r < 4; ++r) {
                    int row = m0 + mi * 16 + quad * 4 + r;
                    out[(size_t)row * (NETS * D3) + col] = acc[mi][ni][r] + bv;
                }
            }
        }
    }
}

extern "C" void kernel_launch(void* const* d_in, const int* in_sizes, int n_in,
                              void* d_out, int out_size, void* d_ws, size_t ws_size,
                              hipStream_t stream) {
    const float* x  = (const float*)d_in[0];
    const float* W1 = (const float*)d_in[1];
    const float* b1 = (const float*)d_in[2];
    const float* W2 = (const float*)d_in[3];
    const float* b2 = (const float*)d_in[4];
    const float* W3 = (const float*)d_in[5];
    const float* b3 = (const float*)d_in[6];
    float* out = (float*)d_out;

    // ws layout (fp16): W1h | W2h | W3h  = ~29.4 MB total
    _Float16* W1h = (_Float16*)d_ws;
    _Float16* W2h = W1h + (size_t)W1_N;
    _Float16* W3h = W2h + (size_t)W2_N;

    const int total4 = W1_4 + W2_4 + W3_4;             // 3,670,016
    cvt_weights<<<total4 / 256, 256, 0, stream>>>(W1, W2, W3, W1h, W2h, W3h);

    mlp_fused<<<NETS * (BATCH / MT), 256, 0, stream>>>(x, W1h, b1, W2h, b2, W3h, b3, out);
}

// Round 4
// 235.161 us; speedup vs baseline: 2.3159x; 2.3159x over previous
//
#include <hip/hip_runtime.h>

#define NETS 32
#define BATCH 4096
#define D0 256
#define D1 512
#define D2 512
#define D3 128
#define MT 64            // batch rows per block
#define LDA (D0 + 8)     // 264 halves -> 528 B row stride (4-bank rotation per row)
#define LDH (D1 + 8)     // 520 halves -> 1040 B row stride

using half8 = __attribute__((ext_vector_type(8))) _Float16;
using half4 = __attribute__((ext_vector_type(4))) _Float16;
using f32x4 = __attribute__((ext_vector_type(4))) float;

#define W1_N (NETS * D1 * D0)   // 4,194,304
#define W2_N (NETS * D2 * D1)   // 8,388,608
#define W3_N (NETS * D3 * D2)   // 2,097,152

// ---------------- fp32 -> fp16 cast + fragment swizzle ----------------
// Swizzled layout: fragment f = ((net*4 + w)*NF + kk*NI + ni), 512 halves each.
// Within a fragment, lane l (l = quad*16 + lane16) owns halves [l*8, l*8+8) =
// source W[net][w*NWCH + ni*16 + lane16][kk*32 + quad*8 .. +8).
// => every wave B-load in the main kernel is one contiguous 1-KB transaction.
__global__ void cvt_weights(const float* __restrict__ W1, const float* __restrict__ W2,
                            const float* __restrict__ W3,
                            _Float16* __restrict__ W1h, _Float16* __restrict__ W2h,
                            _Float16* __restrict__ W3h) {
    const int i = blockIdx.x * blockDim.x + threadIdx.x;   // one 16-B frag-slice per thread
    constexpr int T1 = W1_N / 8, T2 = W2_N / 8, T3 = W3_N / 8;
    const float* src;
    _Float16* dst;
    if (i < T1) {
        // L1: K=256, NI=8, NF=64, n-chunk 128/wave
        int u = i, l = u & 63, f = u >> 6;
        int kkni = f & 63, netw = f >> 6;
        int ni = kkni & 7, kk = kkni >> 3;
        int net = netw >> 2, w = netw & 3;
        int n = w * 128 + ni * 16 + (l & 15);
        int k = kk * 32 + (l >> 4) * 8;
        src = W1 + (size_t)net * D1 * D0 + (size_t)n * D0 + k;
        dst = W1h + (size_t)f * 512 + l * 8;
    } else if (i < T1 + T2) {
        // L2: K=512, NI=8, NF=128
        int u = i - T1, l = u & 63, f = u >> 6;
        int kkni = f & 127, netw = f >> 7;
        int ni = kkni & 7, kk = kkni >> 3;
        int net = netw >> 2, w = netw & 3;
        int n = w * 128 + ni * 16 + (l & 15);
        int k = kk * 32 + (l >> 4) * 8;
        src = W2 + (size_t)net * D2 * D1 + (size_t)n * D1 + k;
        dst = W2h + (size_t)f * 512 + l * 8;
    } else {
        // L3: K=512, NI=2, NF=32, n-chunk 32/wave
        int u = i - T1 - T2, l = u & 63, f = u >> 6;
        int kkni = f & 31, netw = f >> 5;
        int ni = kkni & 1, kk = kkni >> 1;
        int net = netw >> 2, w = netw & 3;
        int n = w * 32 + ni * 16 + (l & 15);
        int k = kk * 32 + (l >> 4) * 8;
        src = W3 + (size_t)net * D3 * D2 + (size_t)n * D2 + k;
        dst = W3h + (size_t)f * 512 + l * 8;
    }
    float4 v0 = *reinterpret_cast<const float4*>(src);
    float4 v1 = *reinterpret_cast<const float4*>(src + 4);
    half8 o;
    o[0] = (_Float16)v0.x; o[1] = (_Float16)v0.y; o[2] = (_Float16)v0.z; o[3] = (_Float16)v0.w;
    o[4] = (_Float16)v1.x; o[5] = (_Float16)v1.y; o[6] = (_Float16)v1.z; o[7] = (_Float16)v1.w;
    *reinterpret_cast<half8*>(dst) = o;
}

// ---------------- software-pipelined layer, coalesced B stream ----------------
// wl points at this (net,wave)'s first fragment + l*8. Fragments are consumed
// linearly: f = kk*NI + ni. Prefetch G fragments one group ahead.
template<int K, int NI, int G, int MI>
__device__ __forceinline__ void layer_mfma(const _Float16* As, int lda,
                                           const _Float16* __restrict__ wl,
                                           int lane16, int quad,
                                           f32x4 (&acc)[MI][NI]) {
    constexpr int NFR = (K / 32) * NI;
    constexpr int STEPS = NFR / G;
    half8 bcur[G], bnxt[G];
    half8 a[MI];
#pragma unroll
    for (int g = 0; g < G; ++g)
        bcur[g] = *reinterpret_cast<const half8*>(wl + (size_t)g * 512);
#pragma unroll
    for (int s = 0; s < STEPS; ++s) {
        const int fb = s * G;
        if (s + 1 < STEPS) {
#pragma unroll
            for (int g = 0; g < G; ++g)
                bnxt[g] = *reinterpret_cast<const half8*>(wl + (size_t)(fb + G + g) * 512);
        }
        if (fb % NI == 0) {
            const int kk = fb / NI;
#pragma unroll
            for (int mi = 0; mi < MI; ++mi)
                a[mi] = *reinterpret_cast<const half8*>(
                    As + (mi * 16 + lane16) * lda + kk * 32 + quad * 8);
        }
#pragma unroll
        for (int g = 0; g < G; ++g) {
            const int ni = (fb + g) % NI;
#pragma unroll
            for (int mi = 0; mi < MI; ++mi)
                acc[mi][ni] = __builtin_amdgcn_mfma_f32_16x16x32_f16(a[mi], bcur[g], acc[mi][ni], 0, 0, 0);
        }
        if (s + 1 < STEPS) {
#pragma unroll
            for (int g = 0; g < G; ++g) bcur[g] = bnxt[g];
        }
    }
}

template<int MI, int NI>
__device__ __forceinline__ void store_act(f32x4 (&acc)[MI][NI], const float* __restrict__ bias,
                                          _Float16* dst, int ldd, int n_base,
                                          int lane16, int quad) {
#pragma unroll
    for (int ni = 0; ni < NI; ++ni) {
        float bv = bias[n_base + ni * 16 + lane16];
        int col = n_base + ni * 16 + lane16;
#pragma unroll
        for (int mi = 0; mi < MI; ++mi) {
#pragma unroll
            for (int r = 0; r < 4; ++r) {
                float v = acc[mi][ni][r] + bv;
                v = fmaxf(v, 0.0f);                        // relu
                int row = mi * 16 + quad * 4 + r;
                dst[row * ldd + col] = (_Float16)v;
            }
        }
    }
}

// ---------------- fused 3-layer MLP, single in-place LDS buffer ----------------
__global__ __launch_bounds__(256, 2) void mlp_fused(
    const float* __restrict__ X,
    const _Float16* __restrict__ W1h, const float* __restrict__ b1,
    const _Float16* __restrict__ W2h, const float* __restrict__ b2,
    const _Float16* __restrict__ W3h, const float* __restrict__ b3,
    float* __restrict__ out) {
    __shared__ __align__(16) _Float16 buf[MT * LDH];   // X (LDA layout) -> H1 -> H2 (LDH)

    const int tid = threadIdx.x;
    const int w = tid >> 6;
    const int l = tid & 63;
    const int lane16 = l & 15;
    const int quad = l >> 4;

    // XCD-locality: dispatch round-robins blockIdx over 8 XCDs -> 4 nets/XCD
    // (3.7 MB fp16 weights per XCD-L2).
    const int bb = blockIdx.x;            // 0..2047
    const int xcd = bb & 7;
    const int s = bb >> 3;                // 0..255
    const int net = xcd * 4 + (s >> 6);   // 0..31
    const int mt = s & 63;                // 0..63
    const int m0 = mt * MT;

    // ---- stage X tile [MT][D0] fp32 -> fp16 into buf (LDA layout) ----
    // MT*D0/4 = 4096 float4 chunks; 256 threads x 16 iters.
    {
        const float* xsrc = X + (size_t)m0 * D0;
#pragma unroll
        for (int it = 0; it < 16; ++it) {
            int chunk = it * 256 + tid;   // 0..4095; 64 float4 per row
            int row = chunk >> 6;
            int c4 = chunk & 63;
            float4 v = *reinterpret_cast<const float4*>(xsrc + row * D0 + c4 * 4);
            half4 o;
            o[0] = (_Float16)v.x; o[1] = (_Float16)v.y;
            o[2] = (_Float16)v.z; o[3] = (_Float16)v.w;
            *reinterpret_cast<half4*>(&buf[row * LDA + c4 * 4]) = o;
        }
    }
    __syncthreads();

    // ---- layer 1: H1 = relu(X @ W1^T + b1), K=256, N=512 (wave owns 128 cols) ----
    {
        f32x4 acc[4][8] = {};
        const _Float16* wl = W1h + ((size_t)(net * 4 + w) * 64) * 512 + l * 8;
        layer_mfma<D0, 8, 4, 4>(buf, LDA, wl, lane16, quad, acc);
        __syncthreads();                               // all X reads done
        store_act<4, 8>(acc, b1 + net * D1, buf, LDH, w * 128, lane16, quad);
    }
    __syncthreads();

    // ---- layer 2: H2 = relu(H1 @ W2^T + b2), K=512, N=512 ----
    {
        f32x4 acc[4][8] = {};
        const _Float16* wl = W2h + ((size_t)(net * 4 + w) * 128) * 512 + l * 8;
        layer_mfma<D1, 8, 4, 4>(buf, LDH, wl, lane16, quad, acc);
        __syncthreads();                               // all H1 reads done
        store_act<4, 8>(acc, b2 + net * D2, buf, LDH, w * 128, lane16, quad);
    }
    __syncthreads();

    // ---- layer 3: out = H2 @ W3^T + b3, K=512, N=128 (wave owns 32 cols) ----
    {
        f32x4 acc[4][2] = {};
        const _Float16* wl = W3h + ((size_t)(net * 4 + w) * 32) * 512 + l * 8;
        layer_mfma<D2, 2, 2, 4>(buf, LDH, wl, lane16, quad, acc);
        const int n_base = w * 32;
#pragma unroll
        for (int ni = 0; ni < 2; ++ni) {
            float bv = b3[net * D3 + n_base + ni * 16 + lane16];
            int col = net * D3 + n_base + ni * 16 + lane16;
#pragma unroll
            for (int mi = 0; mi < 4; ++mi) {
#pragma unroll
                for (int r = 0; r < 4; ++r) {
                    int row = m0 + mi * 16 + quad * 4 + r;
                    out[(size_t)row * (NETS * D3) + col] = acc[mi][ni][r] + bv;
                }
            }
        }
    }
}

extern "C" void kernel_launch(void* const* d_in, const int* in_sizes, int n_in,
                              void* d_out, int out_size, void* d_ws, size_t ws_size,
                              hipStream_t stream) {
    const float* x  = (const float*)d_in[0];
    const float* W1 = (const float*)d_in[1];
    const float* b1 = (const float*)d_in[2];
    const float* W2 = (const float*)d_in[3];
    const float* b2 = (const float*)d_in[4];
    const float* W3 = (const float*)d_in[5];
    const float* b3 = (const float*)d_in[6];
    float* out = (float*)d_out;

    // ws layout (fp16, swizzled): W1h | W2h | W3h  = ~29.4 MB total
    _Float16* W1h = (_Float16*)d_ws;
    _Float16* W2h = W1h + (size_t)W1_N;
    _Float16* W3h = W2h + (size_t)W2_N;

    const int totalT = (W1_N + W2_N + W3_N) / 8;       // 1,835,008 threads
    cvt_weights<<<totalT / 256, 256, 0, stream>>>(W1, W2, W3, W1h, W2h, W3h);

    mlp_fused<<<NETS * (BATCH / MT), 256, 0, stream>>>(x, W1h, b1, W2h, b2, W3h, b3, out);
}